// Round 26
// baseline (192.873 us; speedup 1.0000x reference)
//
#include <hip/hip_runtime.h>
#include <math.h>

#define NATOMS 10000
#define NEDGES 200000
#define NBINS  40000   // (receiver, species) bins = NATOMS*4
#define SCAN_BLOCKS 40 // 40*1024 >= NBINS
#define NTILES 625     // 16 atoms per tile

typedef __attribute__((ext_vector_type(8))) short short8;   // 8 bf16
typedef __attribute__((ext_vector_type(4))) float f32x4;

__device__ __forceinline__ short8 as_s8(uint4 v) {
    union { uint4 u; short8 s; } x; x.u = v; return x.s;
}

// stage layout per block: stage[t][s][64 padded slots], t = atom in tile.
// padded slots: l0@0(8), l1@8(18), l2@28(20), l3@48(14); pads 26,27,62,63 = 0.
// A-fragment (mfma_f32_16x16x32_bf16): lane l holds A[row=l&15][k=(l>>4)*8+j].
// B-fragment: lane l holds B[k=(l>>4)*8+j][col=l&15].
// D: col=lane&15, row=(lane>>4)*4+reg.
// 16 planes p: p0=l0; p1-3=l1(m=p-1); p4-8=l2(m=p-4); p9-15=l3(m=p-9).
// B shared across m within l: 4 B matrices, sqrt-coeff folded: f_l = (2l+1)^(-1/4).

__device__ __forceinline__ unsigned short f2bf(float f) {
    unsigned int u = __float_as_uint(f);
    u += 0x7FFFu + ((u >> 16) & 1u);   // round-to-nearest-even
    return (unsigned short)(u >> 16);
}

__device__ __forceinline__ float bf2f(unsigned short h) {
    return __uint_as_float(((unsigned int)h) << 16);
}

// blocks [0,40): prep W2f (row-major [80][128] f32). rest: count edges.
__global__ __launch_bounds__(256) void prep_count_kernel(
    const float* __restrict__ emb,
    const float* __restrict__ wm0, const float* __restrict__ wm1,
    const float* __restrict__ wm2, const float* __restrict__ wm3,
    float* __restrict__ W2f,
    const int* __restrict__ receivers, const int* __restrict__ senders,
    const int* __restrict__ species, int* __restrict__ counts)
{
    if (blockIdx.x < 40) {
        int tid = blockIdx.x * 256 + threadIdx.x;
        if (tid >= 10240) return;
        const float* wm; int idx, Nl;
        if (tid < 4096)      { wm = wm0; idx = tid;        Nl = 8; }
        else if (tid < 7168) { wm = wm1; idx = tid - 4096; Nl = 6; }
        else if (tid < 9216) { wm = wm2; idx = tid - 7168; Nl = 4; }
        else                 { wm = wm3; idx = tid - 9216; Nl = 2; }
        int j  = idx & 127;
        int sn = idx >> 7;
        int n  = sn % Nl;
        float acc = 0.0f;
        #pragma unroll
        for (int c = 0; c < 16; ++c)
            acc = fmaf(wm[(n*16 + c)*128 + j], emb[(sn / Nl)*16 + c], acc);
        W2f[tid] = acc;   // == row-major [80][128]
    } else {
        int e = (blockIdx.x - 40) * 256 + threadIdx.x;
        if (e < NEDGES) {
            int key = receivers[e] * 4 + species[senders[e]];
            atomicAdd(&counts[key], 1);
        }
    }
}

// Pack B-fragments: 4 l-values x 8 ctiles x 64 lanes x 4 words = 8192 threads.
__global__ __launch_bounds__(256) void pack_b_kernel(
    const float* __restrict__ W2f, unsigned int* __restrict__ Bfb)
{
    int tid = blockIdx.x * 256 + threadIdx.x;
    if (tid >= 4*8*64*4) return;
    const int q  = tid & 3;
    const int l  = (tid >> 2) & 63;
    const int ct = (tid >> 8) & 7;
    const int lv = tid >> 11;          // l value 0..3
    int K, lbase; float f;
    if (lv == 0)      { K = 32; lbase = 0;  f = 1.0f; }
    else if (lv == 1) { K = 24; lbase = 32; f = 0.75983568565f; }  // 3^-1/4
    else if (lv == 2) { K = 16; lbase = 56; f = 0.66874030497f; }  // 5^-1/4
    else              { K = 8;  lbase = 72; f = 0.61478815296f; }  // 7^-1/4
    const int col = ct*16 + (l & 15);
    unsigned int lo = 0, hi = 0;
    const int k0 = (l >> 4)*8 + 2*q;
    if (k0 < K)     lo = f2bf(W2f[(lbase + k0)*128 + col] * f);
    if (k0 + 1 < K) hi = f2bf(W2f[(lbase + k0 + 1)*128 + col] * f);
    Bfb[((lv*8 + ct)*64 + l)*4 + q] = lo | (hi << 16);
}

__global__ __launch_bounds__(1024) void scan1_kernel(
    const int* __restrict__ counts, int* __restrict__ offsets,
    int* __restrict__ blocksums)
{
    __shared__ int sh[1024];
    const int t = threadIdx.x;
    const int idx = blockIdx.x * 1024 + t;
    const int v = (idx < NBINS) ? counts[idx] : 0;
    sh[t] = v;
    __syncthreads();
    for (int off = 1; off < 1024; off <<= 1) {
        int u = (t >= off) ? sh[t - off] : 0;
        __syncthreads();
        sh[t] += u;
        __syncthreads();
    }
    if (idx < NBINS) offsets[idx] = sh[t] - v;   // block-local exclusive
    if (t == 1023) blocksums[blockIdx.x] = sh[1023];
}

__global__ __launch_bounds__(1024) void scan3_kernel(
    int* __restrict__ offsets, int* __restrict__ cursor,
    const int* __restrict__ blocksums)
{
    __shared__ int sbase;
    if (threadIdx.x == 0) {
        int b = 0;
        for (int k = 0; k < (int)blockIdx.x; ++k) b += blocksums[k];
        sbase = b;
    }
    __syncthreads();
    const int idx = blockIdx.x * 1024 + threadIdx.x;
    if (idx < NBINS) {
        int o = offsets[idx] + sbase;
        offsets[idx] = o;
        cursor[idx]  = o;
    }
    if (idx == 0) offsets[NBINS] = NEDGES;
}

__global__ __launch_bounds__(256) void scatter_kernel(
    const int* __restrict__ receivers, const int* __restrict__ senders,
    const int* __restrict__ species, int* __restrict__ cursor,
    int* __restrict__ csr)
{
    int e = blockIdx.x * 256 + threadIdx.x;
    if (e < NEDGES) {
        int key = receivers[e] * 4 + species[senders[e]];
        int p = atomicAdd(&cursor[key], 1);
        csr[p] = e;
    }
}

template<int K, int NL, int SB, int ST>
__device__ __forceinline__ uint4 packPlane(const float* stage, int l2) {
    const int t  = l2 & 15;
    const int kb = (l2 >> 4) * 8;
    unsigned int w[4];
    #pragma unroll
    for (int q = 0; q < 4; ++q) {
        unsigned int lo = 0, hi = 0;
        const int k0 = kb + 2*q, k1 = k0 + 1;
        if (k0 < K) { const int s = k0/NL, n = k0 - s*NL;
                      lo = f2bf(stage[((t*4 + s) << 6) + SB + n*ST]); }
        if (k1 < K) { const int s = k1/NL, n = k1 - s*NL;
                      hi = f2bf(stage[((t*4 + s) << 6) + SB + n*ST]); }
        w[q] = lo | (hi << 16);
    }
    return make_uint4(w[0], w[1], w[2], w[3]);
}

// FUSED edge-math + T-build. 625 blocks x 256 threads; block = one 16-atom tile.
// Tail packs MFMA A-fragments (16 planes x 64 lanes x 16B) to global.  [r23 proven]
__global__ __launch_bounds__(256) void edge_tbuild_kernel(
    const float* __restrict__ pos,
    const float* __restrict__ wr0, const float* __restrict__ wr1,
    const float* __restrict__ wr2, const float* __restrict__ wr3,
    const int* __restrict__ senders,
    const int* __restrict__ receivers,
    const int* __restrict__ csr,
    const int* __restrict__ off4,
    uint4* __restrict__ Ab)
{
    const int tid  = threadIdx.x;
    const int w    = tid >> 6;
    const int lane = tid & 63;
    const int atomBase = blockIdx.x * 16;
    __shared__ unsigned int raw32[256 * 31];   // 31744 B, stride-31 rows

    int bnd[4][5];
    #pragma unroll
    for (int a = 0; a < 4; ++a)
        #pragma unroll
        for (int s = 0; s < 5; ++s)
            bnd[a][s] = off4[(atomBase + w*4 + a)*4 + s];
    const int blockBeg = off4[atomBase*4];
    const int blockEnd = off4[atomBase*4 + 64];

    float acc[4][4];
    #pragma unroll
    for (int a = 0; a < 4; ++a)
        #pragma unroll
        for (int s = 0; s < 4; ++s) acc[a][s] = 0.0f;

    const int dw   = lane >> 1;            // dword 0..29 (lanes 0..59)
    const int half = lane & 1;

    for (int c = blockBeg; c < blockEnd; c += 256) {
        const int i = c + tid;
        if (i < blockEnd) {
            const int e   = csr[i];
            const int snd = senders[e];
            const int rcv = receivers[e];

            float dx = pos[rcv*3]   - pos[snd*3];
            float dy = pos[rcv*3+1] - pos[snd*3+1];
            float dz = pos[rcv*3+2] - pos[snd*3+2];
            float r = sqrtf(dx*dx + dy*dy + dz*dz + 1e-12f);
            float inv_r = 1.0f / r;
            float x = dx * inv_r, y = dy * inv_r, z = dz * inv_r;

            float xr = fminf(r * 0.2f, 1.0f);
            float s1, c1;
            sincosf(3.14159265358979323846f * xr, &s1, &c1);
            float fcut = 0.5f * (c1 + 1.0f);
            float g = fcut / (xr + 0.001f);

            float bess[8];
            {
                float sm1 = 0.0f, s0 = s1;
                float tc = 2.0f * c1;
                #pragma unroll
                for (int n = 0; n < 8; ++n) {
                    bess[n] = s0 * g;
                    float s2 = tc * s0 - sm1;
                    sm1 = s0; s0 = s2;
                }
            }

            float R0[8], R1[6], R2[4], R3[2];
            #pragma unroll
            for (int n = 0; n < 8; ++n) R0[n] = 0.0f;
            #pragma unroll
            for (int n = 0; n < 6; ++n) R1[n] = 0.0f;
            #pragma unroll
            for (int n = 0; n < 4; ++n) R2[n] = 0.0f;
            #pragma unroll
            for (int n = 0; n < 2; ++n) R3[n] = 0.0f;
            #pragma unroll
            for (int k = 0; k < 8; ++k) {
                float b = bess[k];
                #pragma unroll
                for (int n = 0; n < 8; ++n) R0[n] = fmaf(b, wr0[k*8 + n], R0[n]);
                #pragma unroll
                for (int n = 0; n < 6; ++n) R1[n] = fmaf(b, wr1[k*6 + n], R1[n]);
                #pragma unroll
                for (int n = 0; n < 4; ++n) R2[n] = fmaf(b, wr2[k*4 + n], R2[n]);
                #pragma unroll
                for (int n = 0; n < 2; ++n) R3[n] = fmaf(b, wr3[k*2 + n], R3[n]);
            }

            float xy = x*y, yz = y*z, xz = x*z;
            float x2 = x*x, y2 = y*y, z2 = z*z;
            float sh1v[3] = {0.4886025119029199f*y, 0.4886025119029199f*z, 0.4886025119029199f*x};
            float sh2v[5] = {1.0925484305920792f*xy, 1.0925484305920792f*yz,
                             0.31539156525252005f*(3.0f*z2 - 1.0f),
                             1.0925484305920792f*xz, 0.5462742152960396f*(x2 - y2)};
            float sh3v[7] = {0.5900435899266435f*y*(3.0f*x2 - y2),
                             2.890611442640554f*xy*z,
                             0.4570457994644658f*y*(5.0f*z2 - 1.0f),
                             0.3731763325901154f*z*(5.0f*z2 - 3.0f),
                             0.4570457994644658f*x*(5.0f*z2 - 1.0f),
                             1.445305721320277f*z*(x2 - y2),
                             0.5900435899266435f*x*(x2 - 3.0f*y2)};

            unsigned short h[60];
            #pragma unroll
            for (int n = 0; n < 8; ++n)
                h[n] = f2bf(R0[n] * 0.28209479177387814f);
            #pragma unroll
            for (int n = 0; n < 6; ++n)
                #pragma unroll
                for (int m = 0; m < 3; ++m)
                    h[8 + n*3 + m] = f2bf(R1[n] * sh1v[m]);
            #pragma unroll
            for (int n = 0; n < 4; ++n)
                #pragma unroll
                for (int m = 0; m < 5; ++m)
                    h[26 + n*5 + m] = f2bf(R2[n] * sh2v[m]);
            #pragma unroll
            for (int n = 0; n < 2; ++n)
                #pragma unroll
                for (int m = 0; m < 7; ++m)
                    h[46 + n*7 + m] = f2bf(R3[n] * sh3v[m]);

            unsigned int* dst = &raw32[tid * 31];
            #pragma unroll
            for (int k = 0; k < 30; ++k)
                dst[k] = (unsigned int)h[2*k] | ((unsigned int)h[2*k+1] << 16);
        }
        __syncthreads();

        const int n = (blockEnd - c < 256) ? (blockEnd - c) : 256;
        if (lane < 60) {
            #pragma unroll
            for (int a = 0; a < 4; ++a) {
                #pragma unroll
                for (int s = 0; s < 4; ++s) {
                    const int lo = (bnd[a][s]   > c     ? bnd[a][s]   : c)     - c;
                    const int hi = (bnd[a][s+1] < c + n ? bnd[a][s+1] : c + n) - c;
                    float v = acc[a][s];
                    for (int r = lo; r < hi; ++r) {
                        unsigned int u = raw32[r*31 + dw];
                        v += bf2f(half ? (unsigned short)(u >> 16)
                                       : (unsigned short)(u & 0xFFFFu));
                    }
                    acc[a][s] = v;
                }
            }
        }
        __syncthreads();   // before next chunk overwrites raw32
    }

    // ---- stage T (f32, padded) then pack A-fragments ----
    float* stageF = (float*)raw32;   // [t][s][64] floats, t = w*4+a, 16 KB
    const int pl = lane + (lane >= 26 ? 2 : 0);
    if (lane < 60) {
        #pragma unroll
        for (int a = 0; a < 4; ++a)
            #pragma unroll
            for (int s = 0; s < 4; ++s)
                stageF[(((w*4 + a)*4 + s) << 6) + pl] = acc[a][s];
    } else {
        int p = lane - 60;
        int pi = (p < 2) ? (26 + p) : (62 + (p - 2));
        #pragma unroll
        for (int a = 0; a < 4; ++a)
            #pragma unroll
            for (int s = 0; s < 4; ++s)
                stageF[(((w*4 + a)*4 + s) << 6) + pi] = 0.0f;
    }
    __syncthreads();

    const int l2 = tid & 63;
    const int pg = tid >> 6;        // 0..3
    #pragma unroll
    for (int rep = 0; rep < 4; ++rep) {
        const int p = pg*4 + rep;   // plane 0..15
        uint4 wv;
        switch (p) {
            case 0:  wv = packPlane<32,8, 0,1>(stageF, l2); break;
            case 1:  wv = packPlane<24,6, 8,3>(stageF, l2); break;
            case 2:  wv = packPlane<24,6, 9,3>(stageF, l2); break;
            case 3:  wv = packPlane<24,6,10,3>(stageF, l2); break;
            case 4:  wv = packPlane<16,4,28,5>(stageF, l2); break;
            case 5:  wv = packPlane<16,4,29,5>(stageF, l2); break;
            case 6:  wv = packPlane<16,4,30,5>(stageF, l2); break;
            case 7:  wv = packPlane<16,4,31,5>(stageF, l2); break;
            case 8:  wv = packPlane<16,4,32,5>(stageF, l2); break;
            case 9:  wv = packPlane<8,2,48,7>(stageF, l2); break;
            case 10: wv = packPlane<8,2,49,7>(stageF, l2); break;
            case 11: wv = packPlane<8,2,50,7>(stageF, l2); break;
            case 12: wv = packPlane<8,2,51,7>(stageF, l2); break;
            case 13: wv = packPlane<8,2,52,7>(stageF, l2); break;
            case 14: wv = packPlane<8,2,53,7>(stageF, l2); break;
            default: wv = packPlane<8,2,54,7>(stageF, l2); break;
        }
        Ab[((size_t)blockIdx.x * 16 + p) * 64 + l2] = wv;
    }
}

// MFMA mix, LDS-staged A: 625 blocks x 256 (4 waves); block = one 16-atom
// tile. All 256 threads cooperatively load the tile's 16KB A set into LDS
// (4 independent coalesced dwordx4 each -> one latency), then wave w does
// ctiles {2w, 2w+1}: per plane ds_read_b128 the A-fragment + 2 MFMAs.
__global__ __launch_bounds__(256) void mix_kernel(
    const uint4* __restrict__ Ab,
    const uint4* __restrict__ Bfb,
    const float* __restrict__ emb2,
    const float* __restrict__ w_out,
    const float* __restrict__ comp_weights,
    const float* __restrict__ scaling,
    const int* __restrict__ species,
    const int* __restrict__ batch_seg,
    float* __restrict__ out)
{
    const int tid  = threadIdx.x;
    const int w    = tid >> 6;
    const int lane = tid & 63;
    const int tile = blockIdx.x;
    __shared__ uint4 Al[16 * 64];   // 16 KB

    const uint4* src = Ab + (size_t)tile * 16 * 64;
    #pragma unroll
    for (int k = 0; k < 4; ++k)
        Al[k*256 + tid] = src[k*256 + tid];
    __syncthreads();

    f32x4 sq0 = {0.f, 0.f, 0.f, 0.f};
    f32x4 sq1 = {0.f, 0.f, 0.f, 0.f};
    const f32x4 zero = {0.f, 0.f, 0.f, 0.f};
    const int ct0 = w*2, ct1 = w*2 + 1;

    #pragma unroll
    for (int p = 0; p < 16; ++p) {
        short8 a = as_s8(Al[p*64 + lane]);
        const int lv = (p == 0) ? 0 : (p < 4) ? 1 : (p < 9) ? 2 : 3;
        short8 b0 = as_s8(Bfb[(lv*8 + ct0)*64 + lane]);
        short8 b1 = as_s8(Bfb[(lv*8 + ct1)*64 + lane]);
        f32x4 d0 = __builtin_amdgcn_mfma_f32_16x16x32_bf16(a, b0, zero, 0, 0, 0);
        f32x4 d1 = __builtin_amdgcn_mfma_f32_16x16x32_bf16(a, b1, zero, 0, 0, 0);
        sq0.x = fmaf(d0.x, d0.x, sq0.x); sq0.y = fmaf(d0.y, d0.y, sq0.y);
        sq0.z = fmaf(d0.z, d0.z, sq0.z); sq0.w = fmaf(d0.w, d0.w, sq0.w);
        sq1.x = fmaf(d1.x, d1.x, sq1.x); sq1.y = fmaf(d1.y, d1.y, sq1.y);
        sq1.z = fmaf(d1.z, d1.z, sq1.z); sq1.w = fmaf(d1.w, d1.w, sq1.w);
    }

    const int rowbase = (lane >> 4) * 4;
    const int atomb   = tile * 16;
    const int jcol    = lane & 15;
    int sp4[4];
    #pragma unroll
    for (int r = 0; r < 4; ++r) sp4[r] = species[atomb + rowbase + r];

    float vacc[4] = {0.f, 0.f, 0.f, 0.f};
    {
        const int j0 = ct0*16 + jcol;
        const float wo0 = w_out[j0];
        vacc[0] = fmaf(sq0.x*sq0.x, emb2[sp4[0]*128 + j0] * wo0, vacc[0]);
        vacc[1] = fmaf(sq0.y*sq0.y, emb2[sp4[1]*128 + j0] * wo0, vacc[1]);
        vacc[2] = fmaf(sq0.z*sq0.z, emb2[sp4[2]*128 + j0] * wo0, vacc[2]);
        vacc[3] = fmaf(sq0.w*sq0.w, emb2[sp4[3]*128 + j0] * wo0, vacc[3]);
        const int j1 = ct1*16 + jcol;
        const float wo1 = w_out[j1];
        vacc[0] = fmaf(sq1.x*sq1.x, emb2[sp4[0]*128 + j1] * wo1, vacc[0]);
        vacc[1] = fmaf(sq1.y*sq1.y, emb2[sp4[1]*128 + j1] * wo1, vacc[1]);
        vacc[2] = fmaf(sq1.z*sq1.z, emb2[sp4[2]*128 + j1] * wo1, vacc[2]);
        vacc[3] = fmaf(sq1.w*sq1.w, emb2[sp4[3]*128 + j1] * wo1, vacc[3]);
    }

    // reduce over the 16 lanes of each lane-group (cols of D)
    #pragma unroll
    for (int o = 1; o < 16; o <<= 1) {
        #pragma unroll
        for (int r = 0; r < 4; ++r)
            vacc[r] += __shfl_xor(vacc[r], o, 64);
    }
    if ((lane & 15) == 0) {
        const float sc = scaling[0];
        #pragma unroll
        for (int r = 0; r < 4; ++r) {
            const int atom = atomb + rowbase + r;
            float at = vacc[r] * sc + (w == 0 ? comp_weights[sp4[r]] : 0.0f);
            atomicAdd(&out[batch_seg[atom]], at);
        }
    }
}

extern "C" void kernel_launch(void* const* d_in, const int* in_sizes, int n_in,
                              void* d_out, int out_size, void* d_ws, size_t ws_size,
                              hipStream_t stream)
{
    const float* pos  = (const float*)d_in[0];
    const float* emb  = (const float*)d_in[1];
    const float* wr0  = (const float*)d_in[2];
    const float* wm0  = (const float*)d_in[3];
    const float* wr1  = (const float*)d_in[4];
    const float* wm1  = (const float*)d_in[5];
    const float* wr2  = (const float*)d_in[6];
    const float* wm2  = (const float*)d_in[7];
    const float* wr3  = (const float*)d_in[8];
    const float* wm3  = (const float*)d_in[9];
    const float* emb2 = (const float*)d_in[10];
    const float* wout = (const float*)d_in[11];
    const float* cw   = (const float*)d_in[12];
    const float* scal = (const float*)d_in[13];
    const int* species   = (const int*)d_in[14];
    const int* senders   = (const int*)d_in[15];
    const int* receivers = (const int*)d_in[16];
    const int* batch_seg = (const int*)d_in[17];

    int* counts    = (int*)d_ws;                  // 40064
    int* offsets   = counts + 40064;              // 40064 (needs 40001)
    int* cursor    = offsets + 40064;             // 40064
    int* blocksums = cursor + 40064;              // 64
    int* csr       = blocksums + 64;              // 200000
    float* W2f     = (float*)(csr + 200000);      // 10240 f32 [80][128]
    unsigned int* Bfb = (unsigned int*)(W2f + 10240); // 8192 uints = 32 KB
    uint4* Ab      = (uint4*)(Bfb + 8192);        // 625*16*64 uint4 = 10.24 MB

    hipMemsetAsync(counts, 0, NBINS * sizeof(int), stream);
    hipMemsetAsync(d_out, 0, (size_t)out_size * sizeof(float), stream);

    prep_count_kernel<<<40 + (NEDGES + 255)/256, 256, 0, stream>>>(
        emb, wm0, wm1, wm2, wm3, W2f, receivers, senders, species, counts);
    pack_b_kernel<<<32, 256, 0, stream>>>(W2f, Bfb);
    scan1_kernel<<<SCAN_BLOCKS, 1024, 0, stream>>>(counts, offsets, blocksums);
    scan3_kernel<<<SCAN_BLOCKS, 1024, 0, stream>>>(offsets, cursor, blocksums);
    scatter_kernel<<<(NEDGES + 255)/256, 256, 0, stream>>>(receivers, senders, species, cursor, csr);
    edge_tbuild_kernel<<<NTILES, 256, 0, stream>>>(
        pos, wr0, wr1, wr2, wr3, senders, receivers, csr, offsets, Ab);
    mix_kernel<<<NTILES, 256, 0, stream>>>(
        Ab, (const uint4*)Bfb, emb2, wout, cw, scal, species, batch_seg,
        (float*)d_out);
}

// Round 27
// 76.255 us; speedup vs baseline: 2.5293x; 2.5293x over previous
//
#include <hip/hip_runtime.h>
#include <math.h>

#define NATOMS 10000
#define NEDGES 200000
#define NBINS  40000   // (receiver, species) bins = NATOMS*4
#define SCAN_BLOCKS 40 // 40*1024 >= NBINS

// CSR sorted by (receiver, species). Per-edge 60 bf16 values live only in LDS.
// T tile per atom: 256 bf16 (4 species x 64 PADDED slots), stored as 128 uints.
// word k of species s = slots (2k, 2k+1); slot order l0@0, l1@8, l2@28, l3@48;
// pads at 26,27,62,63 (zeroed). even slot -> low 16 bits.
// W2p layout: 80 rows x 64 float2; row = lbase + s*Nl + n, lbase l0@0,l1@32,l2@56,l3@72.
// float2 = (channel j, channel j+64) for lane j.

__device__ __forceinline__ unsigned short f2bf(float f) {
    unsigned int u = __float_as_uint(f);
    u += 0x7FFFu + ((u >> 16) & 1u);   // round-to-nearest-even
    return (unsigned short)(u >> 16);
}

__device__ __forceinline__ float bf2f(unsigned short h) {
    return __uint_as_float(((unsigned int)h) << 16);
}

// unpack slot idx from a 32-word bf16 species row (LDS or global)
__device__ __forceinline__ float tval(const unsigned int* ts, int idx) {
    unsigned int u = ts[idx >> 1];
    return __uint_as_float((idx & 1) ? (u & 0xFFFF0000u) : (u << 16));
}

// blocks [0,40): prep W2p (10240 elems, float2-pair layout). rest: count edges.
__global__ __launch_bounds__(256) void prep_count_kernel(
    const float* __restrict__ emb,
    const float* __restrict__ wm0, const float* __restrict__ wm1,
    const float* __restrict__ wm2, const float* __restrict__ wm3,
    float* __restrict__ W2p,
    const int* __restrict__ receivers, const int* __restrict__ senders,
    const int* __restrict__ species, int* __restrict__ counts)
{
    if (blockIdx.x < 40) {
        int tid = blockIdx.x * 256 + threadIdx.x;
        if (tid >= 10240) return;
        const float* wm; int idx, Nl, lbase;
        if (tid < 4096)      { wm = wm0; idx = tid;        Nl = 8; lbase = 0;  }
        else if (tid < 7168) { wm = wm1; idx = tid - 4096; Nl = 6; lbase = 32; }
        else if (tid < 9216) { wm = wm2; idx = tid - 7168; Nl = 4; lbase = 56; }
        else                 { wm = wm3; idx = tid - 9216; Nl = 2; lbase = 72; }
        int j  = idx & 127;
        int sn = idx >> 7;
        int n  = sn % Nl;
        float acc = 0.0f;
        #pragma unroll
        for (int c = 0; c < 16; ++c)
            acc = fmaf(wm[(n*16 + c)*128 + j], emb[(sn / Nl)*16 + c], acc);
        int row = lbase + sn;
        W2p[(row*64 + (j & 63))*2 + (j >> 6)] = acc;
    } else {
        int e = (blockIdx.x - 40) * 256 + threadIdx.x;
        if (e < NEDGES) {
            int key = receivers[e] * 4 + species[senders[e]];
            atomicAdd(&counts[key], 1);
        }
    }
}

__global__ __launch_bounds__(1024) void scan1_kernel(
    const int* __restrict__ counts, int* __restrict__ offsets,
    int* __restrict__ blocksums)
{
    __shared__ int sh[1024];
    const int t = threadIdx.x;
    const int idx = blockIdx.x * 1024 + t;
    const int v = (idx < NBINS) ? counts[idx] : 0;
    sh[t] = v;
    __syncthreads();
    for (int off = 1; off < 1024; off <<= 1) {
        int u = (t >= off) ? sh[t - off] : 0;
        __syncthreads();
        sh[t] += u;
        __syncthreads();
    }
    if (idx < NBINS) offsets[idx] = sh[t] - v;   // block-local exclusive
    if (t == 1023) blocksums[blockIdx.x] = sh[1023];
}

// scan2 folded in: each block sums blocksums[0..bid) itself.
__global__ __launch_bounds__(1024) void scan3_kernel(
    int* __restrict__ offsets, int* __restrict__ cursor,
    const int* __restrict__ blocksums)
{
    __shared__ int sbase;
    if (threadIdx.x == 0) {
        int b = 0;
        for (int k = 0; k < (int)blockIdx.x; ++k) b += blocksums[k];
        sbase = b;
    }
    __syncthreads();
    const int idx = blockIdx.x * 1024 + threadIdx.x;
    if (idx < NBINS) {
        int o = offsets[idx] + sbase;
        offsets[idx] = o;
        cursor[idx]  = o;
    }
    if (idx == 0) offsets[NBINS] = NEDGES;
}

__global__ __launch_bounds__(256) void scatter_kernel(
    const int* __restrict__ receivers, const int* __restrict__ senders,
    const int* __restrict__ species, int* __restrict__ cursor,
    int* __restrict__ csr)
{
    int e = blockIdx.x * 256 + threadIdx.x;
    if (e < NEDGES) {
        int key = receivers[e] * 4 + species[senders[e]];
        int p = atomicAdd(&cursor[key], 1);
        csr[p] = e;
    }
}

// FUSED edge-math + T-build. 625 blocks x 256 threads; block owns 16 atoms.
// Output T is packed bf16 (128 uints/atom) via in-LDS staging transpose.
__global__ __launch_bounds__(256) void edge_tbuild_kernel(
    const float* __restrict__ pos,
    const float* __restrict__ wr0, const float* __restrict__ wr1,
    const float* __restrict__ wr2, const float* __restrict__ wr3,
    const int* __restrict__ senders,
    const int* __restrict__ receivers,
    const int* __restrict__ csr,
    const int* __restrict__ off4,
    unsigned int* __restrict__ Tb)
{
    const int tid  = threadIdx.x;
    const int w    = tid >> 6;
    const int lane = tid & 63;
    const int atomBase = blockIdx.x * 16;
    __shared__ unsigned int raw32[256 * 31];   // 31744 B, stride-31 rows

    int bnd[4][5];
    #pragma unroll
    for (int a = 0; a < 4; ++a)
        #pragma unroll
        for (int s = 0; s < 5; ++s)
            bnd[a][s] = off4[(atomBase + w*4 + a)*4 + s];
    const int blockBeg = off4[atomBase*4];
    const int blockEnd = off4[atomBase*4 + 64];

    float acc[4][4];
    #pragma unroll
    for (int a = 0; a < 4; ++a)
        #pragma unroll
        for (int s = 0; s < 4; ++s) acc[a][s] = 0.0f;

    const int dw   = lane >> 1;            // dword 0..29 (lanes 0..59)
    const int half = lane & 1;

    for (int c = blockBeg; c < blockEnd; c += 256) {
        const int i = c + tid;
        if (i < blockEnd) {
            const int e   = csr[i];
            const int snd = senders[e];
            const int rcv = receivers[e];

            float dx = pos[rcv*3]   - pos[snd*3];
            float dy = pos[rcv*3+1] - pos[snd*3+1];
            float dz = pos[rcv*3+2] - pos[snd*3+2];
            float r = sqrtf(dx*dx + dy*dy + dz*dz + 1e-12f);
            float inv_r = 1.0f / r;
            float x = dx * inv_r, y = dy * inv_r, z = dz * inv_r;

            float xr = fminf(r * 0.2f, 1.0f);
            float s1, c1;
            sincosf(3.14159265358979323846f * xr, &s1, &c1);
            float fcut = 0.5f * (c1 + 1.0f);
            float g = fcut / (xr + 0.001f);

            float bess[8];
            {
                float sm1 = 0.0f, s0 = s1;
                float tc = 2.0f * c1;
                #pragma unroll
                for (int n = 0; n < 8; ++n) {
                    bess[n] = s0 * g;
                    float s2 = tc * s0 - sm1;
                    sm1 = s0; s0 = s2;
                }
            }

            float R0[8], R1[6], R2[4], R3[2];
            #pragma unroll
            for (int n = 0; n < 8; ++n) R0[n] = 0.0f;
            #pragma unroll
            for (int n = 0; n < 6; ++n) R1[n] = 0.0f;
            #pragma unroll
            for (int n = 0; n < 4; ++n) R2[n] = 0.0f;
            #pragma unroll
            for (int n = 0; n < 2; ++n) R3[n] = 0.0f;
            #pragma unroll
            for (int k = 0; k < 8; ++k) {
                float b = bess[k];
                #pragma unroll
                for (int n = 0; n < 8; ++n) R0[n] = fmaf(b, wr0[k*8 + n], R0[n]);
                #pragma unroll
                for (int n = 0; n < 6; ++n) R1[n] = fmaf(b, wr1[k*6 + n], R1[n]);
                #pragma unroll
                for (int n = 0; n < 4; ++n) R2[n] = fmaf(b, wr2[k*4 + n], R2[n]);
                #pragma unroll
                for (int n = 0; n < 2; ++n) R3[n] = fmaf(b, wr3[k*2 + n], R3[n]);
            }

            float xy = x*y, yz = y*z, xz = x*z;
            float x2 = x*x, y2 = y*y, z2 = z*z;
            float sh1v[3] = {0.4886025119029199f*y, 0.4886025119029199f*z, 0.4886025119029199f*x};
            float sh2v[5] = {1.0925484305920792f*xy, 1.0925484305920792f*yz,
                             0.31539156525252005f*(3.0f*z2 - 1.0f),
                             1.0925484305920792f*xz, 0.5462742152960396f*(x2 - y2)};
            float sh3v[7] = {0.5900435899266435f*y*(3.0f*x2 - y2),
                             2.890611442640554f*xy*z,
                             0.4570457994644658f*y*(5.0f*z2 - 1.0f),
                             0.3731763325901154f*z*(5.0f*z2 - 3.0f),
                             0.4570457994644658f*x*(5.0f*z2 - 1.0f),
                             1.445305721320277f*z*(x2 - y2),
                             0.5900435899266435f*x*(x2 - 3.0f*y2)};

            unsigned short h[60];
            #pragma unroll
            for (int n = 0; n < 8; ++n)
                h[n] = f2bf(R0[n] * 0.28209479177387814f);
            #pragma unroll
            for (int n = 0; n < 6; ++n)
                #pragma unroll
                for (int m = 0; m < 3; ++m)
                    h[8 + n*3 + m] = f2bf(R1[n] * sh1v[m]);
            #pragma unroll
            for (int n = 0; n < 4; ++n)
                #pragma unroll
                for (int m = 0; m < 5; ++m)
                    h[26 + n*5 + m] = f2bf(R2[n] * sh2v[m]);
            #pragma unroll
            for (int n = 0; n < 2; ++n)
                #pragma unroll
                for (int m = 0; m < 7; ++m)
                    h[46 + n*7 + m] = f2bf(R3[n] * sh3v[m]);

            unsigned int* dst = &raw32[tid * 31];
            #pragma unroll
            for (int k = 0; k < 30; ++k)
                dst[k] = (unsigned int)h[2*k] | ((unsigned int)h[2*k+1] << 16);
        }
        __syncthreads();

        const int n = (blockEnd - c < 256) ? (blockEnd - c) : 256;
        if (lane < 60) {
            #pragma unroll
            for (int a = 0; a < 4; ++a) {
                #pragma unroll
                for (int s = 0; s < 4; ++s) {
                    const int lo = (bnd[a][s]   > c     ? bnd[a][s]   : c)     - c;
                    const int hi = (bnd[a][s+1] < c + n ? bnd[a][s+1] : c + n) - c;
                    float v = acc[a][s];
                    for (int r = lo; r < hi; ++r) {
                        unsigned int u = raw32[r*31 + dw];
                        v += bf2f(half ? (unsigned short)(u >> 16)
                                       : (unsigned short)(u & 0xFFFFu));
                    }
                    acc[a][s] = v;
                }
            }
        }
        __syncthreads();   // before next chunk overwrites raw32
    }

    // ---- pack T to bf16 via LDS staging (reuse raw32 as float stage) ----
    float* stageF = (float*)raw32;   // [w][a][s][64] floats = 16 KB
    const int pl = lane + (lane >= 26 ? 2 : 0);   // packed->padded
    if (lane < 60) {
        #pragma unroll
        for (int a = 0; a < 4; ++a)
            #pragma unroll
            for (int s = 0; s < 4; ++s)
                stageF[(((w*4 + a)*4 + s) << 6) + pl] = acc[a][s];
    } else {
        int p = lane - 60;
        int pi = (p < 2) ? (26 + p) : (62 + (p - 2));
        #pragma unroll
        for (int a = 0; a < 4; ++a)
            #pragma unroll
            for (int s = 0; s < 4; ++s)
                stageF[(((w*4 + a)*4 + s) << 6) + pi] = 0.0f;
    }
    __syncthreads();

    const int wi = lane & 31;        // word index within species row
    const int sh = lane >> 5;        // 0/1
    #pragma unroll
    for (int a = 0; a < 4; ++a) {
        const int atom = atomBase + w*4 + a;
        #pragma unroll
        for (int pass = 0; pass < 2; ++pass) {
            const int s = sh + pass*2;
            const float* src = &stageF[(((w*4 + a)*4 + s) << 6)];
            unsigned int word = (unsigned int)f2bf(src[2*wi])
                              | ((unsigned int)f2bf(src[2*wi + 1]) << 16);
            Tb[(size_t)atom*128 + s*32 + wi] = word;
        }
    }
}

// 250 blocks x 512 threads (8 waves). PURE-DS inner loop (r20 proven, 42us);
// epilogue now writes peratom[] with a PLAIN STORE (no contended atomics).
__global__ __launch_bounds__(512) void mix_kernel(
    const unsigned int* __restrict__ Tb,
    const float* __restrict__ W2p,
    const float* __restrict__ emb2,
    const float* __restrict__ w_out,
    const float* __restrict__ comp_weights,
    const float* __restrict__ scaling,
    const int* __restrict__ species,
    float* __restrict__ peratom)
{
    const int tid  = threadIdx.x;
    const int w    = tid >> 6;
    const int lane = tid & 63;
    __shared__ float2 Wl[5120];        // 80 rows x 64 lanes, 40 KB
    __shared__ unsigned int TlS[5120]; // 40 atoms x 128 words, 20 KB

    const float2* Wg = (const float2*)W2p;
    #pragma unroll
    for (int k = 0; k < 10; ++k) Wl[k*512 + tid] = Wg[k*512 + tid];
    const unsigned int* Tsrc = Tb + (size_t)blockIdx.x * 40 * 128;
    #pragma unroll
    for (int k = 0; k < 10; ++k) TlS[k*512 + tid] = Tsrc[k*512 + tid];
    __syncthreads();

    const float scal = scaling[0];
    const int atom0 = blockIdx.x * 40 + w * 5;

    #pragma unroll 1
    for (int i = 0; i < 5; ++i) {
        const int atom = atom0 + i;
        const unsigned int* tb = &TlS[(w*5 + i) * 128];

        float aa0_0 = 0.f, aa0_1 = 0.f;
        float b1_0[3] = {0.f,0.f,0.f},           b1_1[3] = {0.f,0.f,0.f};
        float b2_0[5] = {0.f,0.f,0.f,0.f,0.f},   b2_1[5] = {0.f,0.f,0.f,0.f,0.f};
        float b3_0[7] = {0.f,0.f,0.f,0.f,0.f,0.f,0.f};
        float b3_1[7] = {0.f,0.f,0.f,0.f,0.f,0.f,0.f};

        #pragma unroll
        for (int s = 0; s < 4; ++s) {
            const unsigned int* ts = tb + s * 32;   // LDS, uniform addr -> broadcast
            #pragma unroll
            for (int n = 0; n < 8; ++n) {
                float tv = tval(ts, n);
                float2 wv = Wl[(s*8+n)*64 + lane];
                aa0_0 = fmaf(wv.x, tv, aa0_0);
                aa0_1 = fmaf(wv.y, tv, aa0_1);
            }
            #pragma unroll
            for (int n = 0; n < 6; ++n) {
                float2 wv = Wl[(32 + s*6+n)*64 + lane];
                #pragma unroll
                for (int m = 0; m < 3; ++m) {
                    float tv = tval(ts, 8 + n*3 + m);
                    b1_0[m] = fmaf(wv.x, tv, b1_0[m]);
                    b1_1[m] = fmaf(wv.y, tv, b1_1[m]);
                }
            }
            #pragma unroll
            for (int n = 0; n < 4; ++n) {
                float2 wv = Wl[(56 + s*4+n)*64 + lane];
                #pragma unroll
                for (int m = 0; m < 5; ++m) {
                    float tv = tval(ts, 28 + n*5 + m);
                    b2_0[m] = fmaf(wv.x, tv, b2_0[m]);
                    b2_1[m] = fmaf(wv.y, tv, b2_1[m]);
                }
            }
            #pragma unroll
            for (int n = 0; n < 2; ++n) {
                float2 wv = Wl[(72 + s*2+n)*64 + lane];
                #pragma unroll
                for (int m = 0; m < 7; ++m) {
                    float tv = tval(ts, 48 + n*7 + m);
                    b3_0[m] = fmaf(wv.x, tv, b3_0[m]);
                    b3_1[m] = fmaf(wv.y, tv, b3_1[m]);
                }
            }
        }

        float Bj0 = aa0_0 * aa0_0;
        float Bj1 = aa0_1 * aa0_1;
        Bj0 += (b1_0[0]*b1_0[0] + b1_0[1]*b1_0[1] + b1_0[2]*b1_0[2]) * 0.57735026918962576f;
        Bj1 += (b1_1[0]*b1_1[0] + b1_1[1]*b1_1[1] + b1_1[2]*b1_1[2]) * 0.57735026918962576f;
        {
            float s0 = 0.f, s1v = 0.f;
            #pragma unroll
            for (int m = 0; m < 5; ++m) { s0 = fmaf(b2_0[m], b2_0[m], s0); s1v = fmaf(b2_1[m], b2_1[m], s1v); }
            Bj0 += s0 * 0.44721359549995794f;
            Bj1 += s1v * 0.44721359549995794f;
        }
        {
            float s0 = 0.f, s1v = 0.f;
            #pragma unroll
            for (int m = 0; m < 7; ++m) { s0 = fmaf(b3_0[m], b3_0[m], s0); s1v = fmaf(b3_1[m], b3_1[m], s1v); }
            Bj0 += s0 * 0.37796447300922725f;
            Bj1 += s1v * 0.37796447300922725f;
        }

        const int sp = species[atom];
        float v = Bj0 * Bj0 * emb2[sp*128 + lane] * w_out[lane]
                + Bj1 * Bj1 * emb2[sp*128 + lane + 64] * w_out[lane + 64];

        #pragma unroll
        for (int o = 32; o > 0; o >>= 1) v += __shfl_down(v, o, 64);
        if (lane == 0)
            peratom[atom] = fmaf(v, scal, comp_weights[sp]);   // plain store
    }
}

// Reduce peratom -> out via LDS partials; <=1280 global atomics total.
__global__ __launch_bounds__(1024) void outsum_kernel(
    const float* __restrict__ peratom,
    const int* __restrict__ batch_seg,
    float* __restrict__ out)
{
    __shared__ float sacc[128];
    const int t = threadIdx.x;
    if (t < 128) sacc[t] = 0.0f;
    __syncthreads();
    const int i = blockIdx.x * 1024 + t;
    if (i < NATOMS) atomicAdd(&sacc[batch_seg[i]], peratom[i]);
    __syncthreads();
    if (t < 128) atomicAdd(&out[t], sacc[t]);
}

extern "C" void kernel_launch(void* const* d_in, const int* in_sizes, int n_in,
                              void* d_out, int out_size, void* d_ws, size_t ws_size,
                              hipStream_t stream)
{
    const float* pos  = (const float*)d_in[0];
    const float* emb  = (const float*)d_in[1];
    const float* wr0  = (const float*)d_in[2];
    const float* wm0  = (const float*)d_in[3];
    const float* wr1  = (const float*)d_in[4];
    const float* wm1  = (const float*)d_in[5];
    const float* wr2  = (const float*)d_in[6];
    const float* wm2  = (const float*)d_in[7];
    const float* wr3  = (const float*)d_in[8];
    const float* wm3  = (const float*)d_in[9];
    const float* emb2 = (const float*)d_in[10];
    const float* wout = (const float*)d_in[11];
    const float* cw   = (const float*)d_in[12];
    const float* scal = (const float*)d_in[13];
    const int* species   = (const int*)d_in[14];
    const int* senders   = (const int*)d_in[15];
    const int* receivers = (const int*)d_in[16];
    const int* batch_seg = (const int*)d_in[17];

    int* counts    = (int*)d_ws;                  // 40064
    int* offsets   = counts + 40064;              // 40064 (needs 40001)
    int* cursor    = offsets + 40064;             // 40064
    int* blocksums = cursor + 40064;              // 64
    int* csr       = blocksums + 64;              // 200000
    float* W2p     = (float*)(csr + 200000);      // 10240 floats
    unsigned int* Tb = (unsigned int*)(W2p + 10240); // 10000*128 uints = 5.12 MB
    float* peratom = (float*)(Tb + (size_t)NATOMS * 128); // 10000 floats

    hipMemsetAsync(counts, 0, NBINS * sizeof(int), stream);
    hipMemsetAsync(d_out, 0, (size_t)out_size * sizeof(float), stream);

    prep_count_kernel<<<40 + (NEDGES + 255)/256, 256, 0, stream>>>(
        emb, wm0, wm1, wm2, wm3, W2p, receivers, senders, species, counts);
    scan1_kernel<<<SCAN_BLOCKS, 1024, 0, stream>>>(counts, offsets, blocksums);
    scan3_kernel<<<SCAN_BLOCKS, 1024, 0, stream>>>(offsets, cursor, blocksums);
    scatter_kernel<<<(NEDGES + 255)/256, 256, 0, stream>>>(receivers, senders, species, cursor, csr);
    edge_tbuild_kernel<<<NATOMS/16, 256, 0, stream>>>(
        pos, wr0, wr1, wr2, wr3, senders, receivers, csr, offsets, Tb);
    mix_kernel<<<250, 512, 0, stream>>>(
        Tb, W2p, emb2, wout, cw, scal, species, peratom);
    outsum_kernel<<<(NATOMS + 1023)/1024, 1024, 0, stream>>>(
        peratom, batch_seg, (float*)d_out);
}